// Round 3
// baseline (53.733 us; speedup 1.0000x reference)
//
#include <hip/hip_runtime.h>
#include <hip/hip_bf16.h>

namespace {
constexpr int kH = 128, kW = 128, kN = 4096, kB = 2;
constexpr int kHW = kH * kW;                 // 16384
constexpr float kF = 500.0f, kC = 64.0f;     // FX=FY, CX=CY
constexpr float kLog2e = 1.4426950408889634f;
constexpr int kVLen = kB * kW * kN;          // 1,048,576 elems (Vt: [b][x][n] bf16)
constexpr int kALen = kB * 4 * kH * kN;      // 4,194,304 elems (A4: [b][c][y][n] bf16)
constexpr int kKS = 16;                      // K splits
constexpr int kPixAll = kB * kHW;            // 32768 pixels
}

using short8 = __attribute__((ext_vector_type(8))) short;   // 8 bf16 (4 VGPR)
using f32x4  = __attribute__((ext_vector_type(4))) float;   // MFMA accum

__device__ __forceinline__ unsigned short f2bf(float f) {
  __hip_bfloat16 h = __float2bfloat16(f);
  return *reinterpret_cast<unsigned short*>(&h);
}

// Per-(batch, gaussian) camera transform -> projected center + exp2 coefficient.
__device__ __forceinline__ void gauss_cam(const float* __restrict__ pos,
                                          const float* __restrict__ scl,
                                          const float* __restrict__ qv,
                                          const float* __restrict__ tv,
                                          int b, int n,
                                          float& projx, float& projy, float& kcoef) {
  float qw = qv[4*b+0], qx = qv[4*b+1], qy = qv[4*b+2], qz = qv[4*b+3];
  float inv = rsqrtf(qw*qw + qx*qx + qy*qy + qz*qz);
  qw *= inv; qx *= inv; qy *= inv; qz *= inv;
  float R00 = 1.f - 2.f*(qy*qy + qz*qz);
  float R01 = 2.f*(qx*qy - qz*qw);
  float R02 = 2.f*(qx*qz + qy*qw);
  float R10 = 2.f*(qx*qy + qz*qw);
  float R11 = 1.f - 2.f*(qx*qx + qz*qz);
  float R12 = 2.f*(qy*qz - qx*qw);
  float R20 = 2.f*(qx*qz - qy*qw);
  float R21 = 2.f*(qy*qz + qx*qw);
  float R22 = 1.f - 2.f*(qx*qx + qy*qy);
  float px = pos[3*n+0], py = pos[3*n+1], pz = pos[3*n+2];
  float cxv = R00*px + R01*py + R02*pz + tv[3*b+0];
  float cyv = R10*px + R11*py + R12*pz + tv[3*b+1];
  float czv = R20*px + R21*py + R22*pz + tv[3*b+2];
  float iz = 1.0f / czv;
  projx = cxv * iz * kF + kC;
  projy = cyv * iz * kF + kC;
  float s = scl[n];
  kcoef = -0.5f * kLog2e / (s * s);   // exp(-0.5 d2/var) == exp2(kcoef * d2)
}

// Region 1 (first kVLen threads): Vt[b][x][n] = bf16(exp2(k*(x-px)^2))    (n contiguous)
// Region 2 (next kVLen threads):  A4[b][c][y][n] = bf16(u*{cr,cg,cb,1}),  u = op*exp2(k*(y-py)^2)
__global__ __launch_bounds__(256) void prep_bf16(
    const float* __restrict__ pos, const float* __restrict__ col,
    const float* __restrict__ opa, const float* __restrict__ scl,
    const float* __restrict__ qv,  const float* __restrict__ tv,
    unsigned short* __restrict__ Vt, unsigned short* __restrict__ A4) {
  int t = blockIdx.x * 256 + threadIdx.x;
  if (t < kVLen) {
    int n = t & (kN - 1);
    int x = (t >> 12) & (kW - 1);
    int b = t >> 19;
    float projx, projy, kc;
    gauss_cam(pos, scl, qv, tv, b, n, projx, projy, kc);
    float d = (float)x - projx;
    Vt[t] = f2bf(exp2f(kc * d * d));          // t == (b*kW + x)*kN + n
  } else {
    int t2 = t - kVLen;
    int n = t2 & (kN - 1);
    int y = (t2 >> 12) & (kH - 1);
    int b = t2 >> 19;
    float projx, projy, kc;
    gauss_cam(pos, scl, qv, tv, b, n, projx, projy, kc);
    float d = (float)y - projy;
    float u = opa[n] * exp2f(kc * d * d);
    size_t base = ((size_t)(b * 4) * kH + y) * kN + n;   // c=0 plane
    const size_t pl = (size_t)kH * kN;                    // 524288
    A4[base]        = f2bf(u * col[3*n+0]);
    A4[base + pl]   = f2bf(u * col[3*n+1]);
    A4[base + 2*pl] = f2bf(u * col[3*n+2]);
    A4[base + 3*pl] = f2bf(u);
  }
}

// Grid: kKS*kB*4 blocks. Block (ks,b,c): C_c[128y x 128x] partial over K slice ks.
// 4 waves; wave w owns rows [32w, 32w+32) x all 128 cols.
// Fragment layout (16x16x32 bf16): A lane: row=l&15, k-chunk=(l>>4)*8 (8 contiguous);
// B (from Vt, K-contiguous per x): col=l&15, same k-chunk; D: col=l&15, row=(l>>4)*4+r.
__global__ __launch_bounds__(256) void mfma_accum(
    const unsigned short* __restrict__ A4, const unsigned short* __restrict__ Vt,
    float* __restrict__ Part) {
  int bid = blockIdx.x;
  int c  = bid & 3;
  int b  = (bid >> 2) & 1;
  int ks = bid >> 3;                 // 0..kKS-1
  int wave = __builtin_amdgcn_readfirstlane((int)(threadIdx.x >> 6));
  int lane = (int)(threadIdx.x & 63);
  int r = lane & 15, q = lane >> 4;
  int k0 = ks * (kN / kKS) + q * 8;  // K slice = 256
  const unsigned short* Ab = A4 + (((size_t)(b*4 + c) * kH) + wave*32 + r) * kN + k0;
  const unsigned short* Bb = Vt + ((size_t)b * kW + r) * kN + k0;
  f32x4 acc[2][8] = {};
#pragma unroll
  for (int kk = 0; kk < 8; ++kk) {           // 8 steps of K=32
    short8 a0 = *(const short8*)(Ab + kk * 32);
    short8 a1 = *(const short8*)(Ab + 16 * kN + kk * 32);
#pragma unroll
    for (int s = 0; s < 8; ++s) {
      short8 bv = *(const short8*)(Bb + (size_t)s * 16 * kN + kk * 32);
      acc[0][s] = __builtin_amdgcn_mfma_f32_16x16x32_bf16(a0, bv, acc[0][s], 0, 0, 0);
      acc[1][s] = __builtin_amdgcn_mfma_f32_16x16x32_bf16(a1, bv, acc[1][s], 0, 0, 0);
    }
  }
  // Part plane: [ks][b][c][y][x]
  float* P = Part + (((size_t)ks * kB + b) * 4 + c) * kHW + (wave*32 + q*4) * kW + r;
#pragma unroll
  for (int t = 0; t < 2; ++t)
#pragma unroll
    for (int s = 0; s < 8; ++s)
#pragma unroll
      for (int rr = 0; rr < 4; ++rr)
        P[(t*16 + rr) * kW + s*16] = acc[t][s][rr];
}

__global__ __launch_bounds__(256) void mfma_finalize(
    const float* __restrict__ Part, float* __restrict__ out) {
  int p = blockIdx.x * 256 + threadIdx.x;   // < kPixAll
  int b = p >> 14;
  int yx = p & (kHW - 1);
  float s0 = 0.f, s1 = 0.f, s2 = 0.f, s3 = 0.f;
#pragma unroll
  for (int ks = 0; ks < kKS; ++ks) {
    const float* base = Part + ((size_t)ks * kB + b) * 4 * kHW + yx;
    s0 += base[0];
    s1 += base[kHW];
    s2 += base[2 * kHW];
    s3 += base[3 * kHW];
  }
  float den = fmaxf(s3 + 1e-8f, 1e-8f);
  float inv = 1.0f / den;
  out[(b * 3 + 0) * kHW + yx] = s0 * inv;
  out[(b * 3 + 1) * kHW + yx] = s1 * inv;
  out[(b * 3 + 2) * kHW + yx] = s2 * inv;
}

// ---------- fallback path (tiny workspace): direct per-pixel loop ----------
__global__ __launch_bounds__(256) void fb_params(
    const float* __restrict__ pos, const float* __restrict__ scl,
    const float* __restrict__ qv,  const float* __restrict__ tv,
    const float* __restrict__ opa, float4* __restrict__ Pa) {
  int t = blockIdx.x * 256 + threadIdx.x;   // < kB*kN
  int n = t & (kN - 1);
  int b = t >> 12;
  float px, py, kc;
  gauss_cam(pos, scl, qv, tv, b, n, px, py, kc);
  Pa[t] = make_float4(px, py, kc, opa[n]);
}

__global__ __launch_bounds__(256) void fb_render(
    const float4* __restrict__ Pa, const float* __restrict__ col,
    float* __restrict__ out) {
  int p = blockIdx.x * 256 + threadIdx.x;   // < kB*kHW
  int b = p >> 14;
  int yx = p & (kHW - 1);
  int y = yx >> 7, x = yx & (kW - 1);
  float ar = 0.f, ag = 0.f, ab = 0.f, ad = 0.f;
  for (int n = 0; n < kN; ++n) {
    float4 g = Pa[(b << 12) + n];
    float dx = (float)x - g.x;
    float dy = (float)y - g.y;
    float d2 = fmaf(dx, dx, dy * dy);
    float w = g.w * exp2f(g.z * d2);
    ar = fmaf(w, col[3*n+0], ar);
    ag = fmaf(w, col[3*n+1], ag);
    ab = fmaf(w, col[3*n+2], ab);
    ad += w;
  }
  float den = fmaxf(ad + 1e-8f, 1e-8f);
  float inv = 1.0f / den;
  out[(b * 3 + 0) * kHW + yx] = ar * inv;
  out[(b * 3 + 1) * kHW + yx] = ag * inv;
  out[(b * 3 + 2) * kHW + yx] = ab * inv;
}

extern "C" void kernel_launch(void* const* d_in, const int* in_sizes, int n_in,
                              void* d_out, int out_size, void* d_ws, size_t ws_size,
                              hipStream_t stream) {
  const float* pos = (const float*)d_in[0];
  const float* col = (const float*)d_in[1];
  const float* opa = (const float*)d_in[2];
  const float* scl = (const float*)d_in[3];
  const float* qv  = (const float*)d_in[4];
  const float* tv  = (const float*)d_in[5];
  float* out = (float*)d_out;

  const size_t part_floats = (size_t)kKS * kB * 4 * kHW;     // 2,097,152 (8 MB)
  const size_t need = (size_t)(kVLen + kALen) * 2 + part_floats * 4;   // 18 MB

  if (ws_size >= need) {
    unsigned short* Vt = (unsigned short*)d_ws;
    unsigned short* A4 = Vt + kVLen;
    float* Part = (float*)(A4 + kALen);
    prep_bf16<<<dim3((2 * kVLen) / 256), dim3(256), 0, stream>>>(
        pos, col, opa, scl, qv, tv, Vt, A4);
    mfma_accum<<<dim3(kKS * kB * 4), dim3(256), 0, stream>>>(A4, Vt, Part);
    mfma_finalize<<<dim3(kPixAll / 256), dim3(256), 0, stream>>>(Part, out);
  } else {
    float4* Pa = (float4*)d_ws;   // 128 KB
    fb_params<<<dim3(kB * kN / 256), dim3(256), 0, stream>>>(pos, scl, qv, tv, opa, Pa);
    fb_render<<<dim3(kPixAll / 256), dim3(256), 0, stream>>>(Pa, col, out);
  }
}

// Round 4
// 32.610 us; speedup vs baseline: 1.6478x; 1.6478x over previous
//
#include <hip/hip_runtime.h>
#include <hip/hip_bf16.h>

namespace {
constexpr int kH = 128, kW = 128, kN = 4096, kB = 2;
constexpr int kHW = kH * kW;                 // 16384
constexpr float kF = 500.0f, kC = 64.0f;     // FX=FY, CX=CY
constexpr float kLog2e = 1.4426950408889634f;
constexpr int kKS = 16;                      // K splits (slice = 256)
constexpr int kSL = kN / kKS;                // 256
constexpr int kPixAll = kB * kHW;            // 32768 pixels
}

using short8 = __attribute__((ext_vector_type(8))) short;   // 8 bf16 (4 VGPR)
using f32x4  = __attribute__((ext_vector_type(4))) float;   // MFMA accum

__device__ __forceinline__ unsigned int f2bf(float f) {
  __hip_bfloat16 h = __float2bfloat16(f);
  return (unsigned int)*reinterpret_cast<unsigned short*>(&h);
}

__device__ __forceinline__ void gauss_cam(const float* __restrict__ pos,
                                          const float* __restrict__ scl,
                                          const float* __restrict__ qv,
                                          const float* __restrict__ tv,
                                          int b, int n,
                                          float& projx, float& projy, float& kcoef) {
  float qw = qv[4*b+0], qx = qv[4*b+1], qy = qv[4*b+2], qz = qv[4*b+3];
  float inv = rsqrtf(qw*qw + qx*qx + qy*qy + qz*qz);
  qw *= inv; qx *= inv; qy *= inv; qz *= inv;
  float R00 = 1.f - 2.f*(qy*qy + qz*qz);
  float R01 = 2.f*(qx*qy - qz*qw);
  float R02 = 2.f*(qx*qz + qy*qw);
  float R10 = 2.f*(qx*qy + qz*qw);
  float R11 = 1.f - 2.f*(qx*qx + qz*qz);
  float R12 = 2.f*(qy*qz - qx*qw);
  float R20 = 2.f*(qx*qz - qy*qw);
  float R21 = 2.f*(qy*qz + qx*qw);
  float R22 = 1.f - 2.f*(qx*qx + qy*qy);
  float px = pos[3*n+0], py = pos[3*n+1], pz = pos[3*n+2];
  float cxv = R00*px + R01*py + R02*pz + tv[3*b+0];
  float cyv = R10*px + R11*py + R12*pz + tv[3*b+1];
  float czv = R20*px + R21*py + R22*pz + tv[3*b+2];
  float iz = 1.0f / czv;
  projx = cxv * iz * kF + kC;
  projy = cyv * iz * kF + kC;
  float s = scl[n];
  kcoef = -0.5f * kLog2e / (s * s);   // exp(-0.5 d2/var) == exp2(kcoef * d2)
}

// Grid: kKS*kB*4*2 = 256 blocks. Block (ks, b, c, yhalf):
//   phase 0: 256 gauss_cam params -> LDS
//   phase 1: V[128x][256k], A_c[64y][256k] bf16 tiles -> LDS (XOR-swizzled)
//   phase 2: 16x16x32 bf16 MFMA over the tiles -> f32 Part plane slice
// Part layout: [ks][b][c][y*kW+x] f32 (8 MB)
__global__ __launch_bounds__(512) void fused_kernel(
    const float* __restrict__ pos, const float* __restrict__ col,
    const float* __restrict__ opa, const float* __restrict__ scl,
    const float* __restrict__ qv,  const float* __restrict__ tv,
    float* __restrict__ Part) {
  __shared__ unsigned short Vlds[128 * kSL];   // 64 KB, row stride 512 B
  __shared__ unsigned short Alds[64 * kSL];    // 32 KB
  __shared__ float4 pa[kSL];                   // projx, projy, kc, opacity
  __shared__ float  pc[kSL];                   // col_c (c<3) or 1.0 (den plane)

  int bid = blockIdx.x;
  int yh = bid & 1;
  int c  = (bid >> 1) & 3;
  int b  = (bid >> 3) & 1;
  int ks = bid >> 4;
  int tid = (int)threadIdx.x;
  int n0 = ks * kSL;

  if (tid < kSL) {
    int n = n0 + tid;
    float px_, py_, kc_;
    gauss_cam(pos, scl, qv, tv, b, n, px_, py_, kc_);
    pa[tid] = make_float4(px_, py_, kc_, opa[n]);
    pc[tid] = (c < 3) ? col[3*n + c] : 1.0f;
  }
  __syncthreads();

  // phase 1: each thread owns an n-pair (2 consecutive k), loops rows.
  int np  = tid & 127;
  int sub = tid >> 7;                 // 0..3
  float4 p0 = pa[2*np], p1 = pa[2*np+1];
  float m0 = p0.w * pc[2*np], m1 = p1.w * pc[2*np+1];
  int y0 = yh * 64;
  char* vbase = (char*)Vlds;
  char* abase = (char*)Alds;
#pragma unroll
  for (int i = 0; i < 32; ++i) {      // V rows: x = 0..127
    int x = sub * 32 + i;
    float d0 = (float)x - p0.x, d1 = (float)x - p1.x;
    unsigned v0 = f2bf(exp2f(p0.z * d0 * d0));
    unsigned v1 = f2bf(exp2f(p1.z * d1 * d1));
    int byte = (x * 512 + np * 4) ^ ((x & 15) << 4);
    *(unsigned*)(vbase + byte) = v0 | (v1 << 16);
  }
#pragma unroll
  for (int i = 0; i < 16; ++i) {      // A rows: yl = 0..63 (global y = y0+yl)
    int yl = sub * 16 + i;
    float y = (float)(y0 + yl);
    float e0 = y - p0.y, e1 = y - p1.y;
    unsigned a0 = f2bf(m0 * exp2f(p0.z * e0 * e0));
    unsigned a1 = f2bf(m1 * exp2f(p1.z * e1 * e1));
    int byte = (yl * 512 + np * 4) ^ ((yl & 15) << 4);
    *(unsigned*)(abase + byte) = a0 | (a1 << 16);
  }
  __syncthreads();

  // phase 2: MFMA. wave w: y-tile = w>>1 (16 rows), x-half = w&1 (64 cols).
  int lane = tid & 63, r = lane & 15, q = lane >> 4;
  int w  = tid >> 6;
  int yt = w >> 1, xh = w & 1;
  f32x4 acc[4] = {};
#pragma unroll
  for (int kk = 0; kk < 8; ++kk) {
    int kb2 = (kk * 32 + q * 8) * 2;
    int ab = ((yt * 16 + r) * 512 + kb2) ^ (r << 4);   // (row&15)==r
    short8 av = *(const short8*)(abase + ab);
#pragma unroll
    for (int s = 0; s < 4; ++s) {
      int row = xh * 64 + s * 16 + r;                  // (row&15)==r
      int bb = (row * 512 + kb2) ^ (r << 4);
      short8 bv = *(const short8*)(vbase + bb);
      acc[s] = __builtin_amdgcn_mfma_f32_16x16x32_bf16(av, bv, acc[s], 0, 0, 0);
    }
  }
  float* P = Part + (((size_t)ks * kB + b) * 4 + c) * kHW;
#pragma unroll
  for (int s = 0; s < 4; ++s) {
    int colx = xh * 64 + s * 16 + r;
#pragma unroll
    for (int rr = 0; rr < 4; ++rr) {
      int row = y0 + yt * 16 + q * 4 + rr;             // D: col=lane&15, row=(lane>>4)*4+reg
      P[row * kW + colx] = acc[s][rr];
    }
  }
}

__global__ __launch_bounds__(256) void mfma_finalize(
    const float* __restrict__ Part, float* __restrict__ out) {
  int p = blockIdx.x * 256 + threadIdx.x;   // < kPixAll
  int b = p >> 14;
  int yx = p & (kHW - 1);
  float s0 = 0.f, s1 = 0.f, s2 = 0.f, s3 = 0.f;
#pragma unroll
  for (int ks = 0; ks < kKS; ++ks) {
    const float* base = Part + ((size_t)ks * kB + b) * 4 * kHW + yx;
    s0 += base[0];
    s1 += base[kHW];
    s2 += base[2 * kHW];
    s3 += base[3 * kHW];
  }
  float den = fmaxf(s3 + 1e-8f, 1e-8f);
  float inv = 1.0f / den;
  out[(b * 3 + 0) * kHW + yx] = s0 * inv;
  out[(b * 3 + 1) * kHW + yx] = s1 * inv;
  out[(b * 3 + 2) * kHW + yx] = s2 * inv;
}

// ---------- fallback path (tiny workspace): direct per-pixel loop ----------
__global__ __launch_bounds__(256) void fb_params(
    const float* __restrict__ pos, const float* __restrict__ scl,
    const float* __restrict__ qv,  const float* __restrict__ tv,
    const float* __restrict__ opa, float4* __restrict__ Pa) {
  int t = blockIdx.x * 256 + threadIdx.x;   // < kB*kN
  int n = t & (kN - 1);
  int b = t >> 12;
  float px, py, kc;
  gauss_cam(pos, scl, qv, tv, b, n, px, py, kc);
  Pa[t] = make_float4(px, py, kc, opa[n]);
}

__global__ __launch_bounds__(256) void fb_render(
    const float4* __restrict__ Pa, const float* __restrict__ col,
    float* __restrict__ out) {
  int p = blockIdx.x * 256 + threadIdx.x;   // < kB*kHW
  int b = p >> 14;
  int yx = p & (kHW - 1);
  int y = yx >> 7, x = yx & (kW - 1);
  float ar = 0.f, ag = 0.f, ab = 0.f, ad = 0.f;
  for (int n = 0; n < kN; ++n) {
    float4 g = Pa[(b << 12) + n];
    float dx = (float)x - g.x;
    float dy = (float)y - g.y;
    float d2 = fmaf(dx, dx, dy * dy);
    float w = g.w * exp2f(g.z * d2);
    ar = fmaf(w, col[3*n+0], ar);
    ag = fmaf(w, col[3*n+1], ag);
    ab = fmaf(w, col[3*n+2], ab);
    ad += w;
  }
  float den = fmaxf(ad + 1e-8f, 1e-8f);
  float inv = 1.0f / den;
  out[(b * 3 + 0) * kHW + yx] = ar * inv;
  out[(b * 3 + 1) * kHW + yx] = ag * inv;
  out[(b * 3 + 2) * kHW + yx] = ab * inv;
}

extern "C" void kernel_launch(void* const* d_in, const int* in_sizes, int n_in,
                              void* d_out, int out_size, void* d_ws, size_t ws_size,
                              hipStream_t stream) {
  const float* pos = (const float*)d_in[0];
  const float* col = (const float*)d_in[1];
  const float* opa = (const float*)d_in[2];
  const float* scl = (const float*)d_in[3];
  const float* qv  = (const float*)d_in[4];
  const float* tv  = (const float*)d_in[5];
  float* out = (float*)d_out;

  const size_t part_bytes = (size_t)kKS * kB * 4 * kHW * 4;   // 8 MB

  if (ws_size >= part_bytes) {
    float* Part = (float*)d_ws;
    fused_kernel<<<dim3(kKS * kB * 4 * 2), dim3(512), 0, stream>>>(
        pos, col, opa, scl, qv, tv, Part);
    mfma_finalize<<<dim3(kPixAll / 256), dim3(256), 0, stream>>>(Part, out);
  } else {
    float4* Pa = (float4*)d_ws;   // 128 KB
    fb_params<<<dim3(kB * kN / 256), dim3(256), 0, stream>>>(pos, scl, qv, tv, opa, Pa);
    fb_render<<<dim3(kPixAll / 256), dim3(256), 0, stream>>>(Pa, col, out);
  }
}

// Round 6
// 17.477 us; speedup vs baseline: 3.0746x; 1.8659x over previous
//
#include <hip/hip_runtime.h>
#include <hip/hip_bf16.h>

namespace {
constexpr int kH = 128, kW = 128, kN = 4096, kB = 2;
constexpr int kHW = kH * kW;                 // 16384
constexpr float kF = 500.0f, kC = 64.0f;     // FX=FY, CX=CY
constexpr float kLog2e = 1.4426950408889634f;
constexpr int kSL = 1024;                    // n-slice staged in LDS
constexpr int kNS = kN / kSL;                // 4 slices
}

using short8 = __attribute__((ext_vector_type(8))) short;   // 8 bf16 (4 VGPR)
using f32x4  = __attribute__((ext_vector_type(4))) float;   // MFMA accum

__device__ __forceinline__ float frcp(float x) {
  float r;
  asm("v_rcp_f32_e32 %0, %1" : "=v"(r) : "v"(x));
  return r;   // ~1e-7 rel err: fine under bf16 operand rounding
}

__device__ __forceinline__ unsigned cvt_pk_bf16(float lo, float hi) {
  unsigned r;
  asm("v_cvt_pk_bf16_f32 %0, %1, %2" : "=v"(r) : "v"(lo), "v"(hi));
  return r;   // packed {hi,lo} bf16 in one u32
}

// ONE kernel: grid 256 = (b:2)x(ytile:16)x(xtile:8), 512 threads (8 waves).
// Block output: 4 channels x 8 y-rows x 16 x-cols, full K=4096.
// Per slice (1024 n): thread t evaluates params+V+A for n-pair (2t,2t+1) into
// swizzled LDS; waves run 16x16x32 bf16 MFMA (2 tiles x 4-way K-split);
// final LDS reduction + divide writes d_out directly. No workspace.
__global__ __launch_bounds__(512) void render_one(
    const float* __restrict__ pos, const float* __restrict__ col,
    const float* __restrict__ opa, const float* __restrict__ scl,
    const float* __restrict__ qv,  const float* __restrict__ tv,
    float* __restrict__ out) {
  __shared__ unsigned short Vl[16 * kSL];    // 32 KB: row = xr (16), stride 2048 B
  __shared__ unsigned short Al[32 * kSL];    // 64 KB: row = c*8+yl (32)
  __shared__ float Sred[2 * 4 * 256];        // 8 KB: [tile][kq][lane*4+reg]

  const int bid = blockIdx.x;
  const int xt = bid & 7;
  const int yt = (bid >> 3) & 15;
  const int b  = bid >> 7;
  const int x0 = xt * 16, y0 = yt * 8;
  const int tid = (int)threadIdx.x;

  // camera rotation (block-uniform; cheap to compute per thread)
  float qw = qv[4*b+0], qx = qv[4*b+1], qy = qv[4*b+2], qz = qv[4*b+3];
  float qn = rsqrtf(qw*qw + qx*qx + qy*qy + qz*qz);
  qw *= qn; qx *= qn; qy *= qn; qz *= qn;
  const float R00 = 1.f - 2.f*(qy*qy + qz*qz);
  const float R01 = 2.f*(qx*qy - qz*qw);
  const float R02 = 2.f*(qx*qz + qy*qw);
  const float R10 = 2.f*(qx*qy + qz*qw);
  const float R11 = 1.f - 2.f*(qx*qx + qz*qz);
  const float R12 = 2.f*(qy*qz - qx*qw);
  const float R20 = 2.f*(qx*qz - qy*qw);
  const float R21 = 2.f*(qy*qz + qx*qw);
  const float R22 = 1.f - 2.f*(qx*qx + qy*qy);
  const float t0 = tv[3*b+0], t1 = tv[3*b+1], t2 = tv[3*b+2];

  const int lane = tid & 63;
  const int r = lane & 15, q = lane >> 4;
  const int w = tid >> 6;
  const int tile = w & 1;         // A-row tile (rows tile*16 .. +15)
  const int kq = w >> 1;          // K quarter within slice
  f32x4 acc = {0.f, 0.f, 0.f, 0.f};

  char* vbase = (char*)Vl;
  char* abase = (char*)Al;

  for (int s = 0; s < kNS; ++s) {
    if (s) __syncthreads();                  // prior slice's reads done
    // ---- eval phase: n-pair (n0+2*tid, n0+2*tid+1) ----
    const int n0 = s * kSL;
    const int na = n0 + 2 * tid, nb = na + 1;
    // camera transform for both n
    float pxa = pos[3*na], pya = pos[3*na+1], pza = pos[3*na+2];
    float pxb = pos[3*nb], pyb = pos[3*nb+1], pzb = pos[3*nb+2];
    float cza = R20*pxa + R21*pya + R22*pza + t2;
    float czb = R20*pxb + R21*pyb + R22*pzb + t2;
    float iza = frcp(cza), izb = frcp(czb);
    float prxa = (R00*pxa + R01*pya + R02*pza + t0) * iza * kF + kC;
    float prxb = (R00*pxb + R01*pyb + R02*pzb + t0) * izb * kF + kC;
    float prya = (R10*pxa + R11*pya + R12*pza + t1) * iza * kF + kC;
    float pryb = (R10*pxb + R11*pyb + R12*pzb + t1) * izb * kF + kC;
    float sa = scl[na], sb = scl[nb];
    float ka = -0.5f * kLog2e * frcp(sa * sa);   // exp(-.5 d2/var) = exp2(k d2)
    float kb = -0.5f * kLog2e * frcp(sb * sb);
    float oa = opa[na], ob = opa[nb];

    // V rows: x = x0..x0+15, incremental parabola e(x)=k*(x-px)^2
    {
      float da = (float)x0 - prxa, db = (float)x0 - prxb;
      float ea = ka * da * da,      eb = kb * db * db;
      float ga = 2.f * ka * da,     gb = 2.f * kb * db;
#pragma unroll
      for (int xr = 0; xr < 16; ++xr) {
        unsigned pk = cvt_pk_bf16(exp2f(ea), exp2f(eb));
        int byte = (xr * 2048 + tid * 4) ^ ((xr & 15) << 4);
        *(unsigned*)(vbase + byte) = pk;
        ea += ga + ka; ga += 2.f * ka;
        eb += gb + kb; gb += 2.f * kb;
      }
    }
    // A rows: row = c*8+yl; weights m_c = opa * {cr,cg,cb,1}
    {
      float m0a = oa * col[3*na],   m0b = ob * col[3*nb];
      float m1a = oa * col[3*na+1], m1b = ob * col[3*nb+1];
      float m2a = oa * col[3*na+2], m2b = ob * col[3*nb+2];
      float da = (float)y0 - prya, db = (float)y0 - pryb;
      float ea = ka * da * da,      eb = kb * db * db;
      float ga = 2.f * ka * da,     gb = 2.f * kb * db;
#pragma unroll
      for (int yl = 0; yl < 8; ++yl) {
        float wa = exp2f(ea), wb = exp2f(eb);
        int base = yl * 2048 + tid * 4;
        *(unsigned*)(abase + ((base          ) ^ (((yl     ) & 15) << 4))) = cvt_pk_bf16(m0a * wa, m0b * wb);
        *(unsigned*)(abase + ((base + 8 *2048) ^ (((yl +  8) & 15) << 4))) = cvt_pk_bf16(m1a * wa, m1b * wb);
        *(unsigned*)(abase + ((base + 16*2048) ^ (((yl + 16) & 15) << 4))) = cvt_pk_bf16(m2a * wa, m2b * wb);
        *(unsigned*)(abase + ((base + 24*2048) ^ (((yl + 24) & 15) << 4))) = cvt_pk_bf16(oa * wa, ob * wb);  // den: opacity-weighted!
        ea += ga + ka; ga += 2.f * ka;
        eb += gb + kb; gb += 2.f * kb;
      }
    }
    __syncthreads();

    // ---- MFMA phase: wave (tile, kq) consumes n in [kq*256, kq*256+256) ----
#pragma unroll
    for (int kk = 0; kk < 8; ++kk) {
      int koff = kq * 256 + kk * 32 + q * 8;       // elem offset in slice
      int arow = tile * 16 + r;
      int ab = (arow * 2048 + koff * 2) ^ (r << 4);
      int bb = (r    * 2048 + koff * 2) ^ (r << 4);
      short8 av = *(const short8*)(abase + ab);
      short8 bv = *(const short8*)(vbase + bb);
      acc = __builtin_amdgcn_mfma_f32_16x16x32_bf16(av, bv, acc, 0, 0, 0);
    }
  }

  // ---- reduction: Sred[tile][kq][lane*4+reg] ----
  {
    float* dst = Sred + ((tile * 4 + kq) * 256) + lane * 4;
    dst[0] = acc[0]; dst[1] = acc[1]; dst[2] = acc[2]; dst[3] = acc[3];
  }
  __syncthreads();
  {  // stage 1: sum 4 K-partials per element (each thread owns one element)
    int t = tid >> 8, e = tid & 255;
    const float* sp = Sred + t * 4 * 256 + e;
    float v = sp[0] + sp[256] + sp[512] + sp[768];
    Sred[t * 4 * 256 + e] = v;
  }
  __syncthreads();
  if (tid < 384) {   // stage 2: divide + store. D layout: row=(lane>>4)*4+reg, col=lane&15
    int c = tid >> 7, p = tid & 127;
    int yl = p >> 4, xl = p & 15;
    int grow_n = c * 8 + yl;
    int tn = grow_n >> 4, rn = grow_n & 15;
    int en = (((rn >> 2) * 16 + xl) << 2) + (rn & 3);
    int rd = 8 + yl;                              // den rows 24..31 -> tile 1
    int ed = (((rd >> 2) * 16 + xl) << 2) + (rd & 3);
    float num = Sred[tn * 1024 + en];
    float den = Sred[1 * 1024 + ed];
    float dv  = fmaxf(den + 1e-8f, 1e-8f);
    out[(b * 3 + c) * kHW + (y0 + yl) * kW + (x0 + xl)] = num * frcp(dv);
  }
}

extern "C" void kernel_launch(void* const* d_in, const int* in_sizes, int n_in,
                              void* d_out, int out_size, void* d_ws, size_t ws_size,
                              hipStream_t stream) {
  const float* pos = (const float*)d_in[0];
  const float* col = (const float*)d_in[1];
  const float* opa = (const float*)d_in[2];
  const float* scl = (const float*)d_in[3];
  const float* qv  = (const float*)d_in[4];
  const float* tv  = (const float*)d_in[5];
  float* out = (float*)d_out;
  (void)d_ws; (void)ws_size;
  render_one<<<dim3(256), dim3(512), 0, stream>>>(pos, col, opa, scl, qv, tv, out);
}